// Round 7
// baseline (302.595 us; speedup 1.0000x reference)
//
#include <hip/hip_runtime.h>
#include <math.h>

#define NB   8
#define NN   8192
#define NS   2048
#define ND1  128
#define ND2  256
#define NCIN 384
#define NC1  256
#define NC2  128

#define EPS_ITP 1e-8f
#define EPS_INORM 1e-5f

typedef float f32x4 __attribute__((ext_vector_type(4)));
typedef short s16x8 __attribute__((ext_vector_type(8)));
typedef short s16x4 __attribute__((ext_vector_type(4)));
typedef short s16x2 __attribute__((ext_vector_type(2)));

// RNE float->bf16 (finite inputs)
static __device__ __forceinline__ short f2bf(float f) {
    unsigned u = __float_as_uint(f);
    unsigned r = (u + 0x7FFFu + ((u >> 16) & 1u)) >> 16;
    return (short)r;
}
static __device__ __forceinline__ float bflo(unsigned u) { return __uint_as_float(u << 16); }
static __device__ __forceinline__ float bfhi(unsigned u) { return __uint_as_float(u & 0xFFFF0000u); }
// pack 2 f32 -> 2 bf16 in one u32 (lo=a, hi=b), RNE
static __device__ __forceinline__ unsigned pkbf(float a, float b) {
    unsigned r;
    asm("v_cvt_pk_bf16_f32 %0, %1, %2" : "=v"(r) : "v"(a), "v"(b));
    return r;
}

// ---------------------------------------------------------------------------
// Kernel 1: 3-NN + inverse-distance interp + concat -> x bf16 [B][N][384]
// (unchanged — passing)
// ---------------------------------------------------------------------------
__global__ __launch_bounds__(256) void k_knn_interp(
    const float* __restrict__ xyz1, const float* __restrict__ xyz2,
    const float* __restrict__ points1, const float* __restrict__ points2,
    unsigned short* __restrict__ xb)
{
    __shared__ float q[NS * 4];        // 32768 B
    __shared__ float sd[4][64][3];     // 3072 B
    __shared__ int   sl[4][64][3];     // 3072 B
    float (*sw)[3] = (float(*)[3])&sd[0][0][0];
    int   (*si)[3] = (int  (*)[3])&sl[0][0][0];

    const int t  = threadIdx.x;
    const int b  = blockIdx.y;
    const int n0 = blockIdx.x * 64;

    const float* xz2 = xyz2 + b * NS * 3;
    for (int e = t; e < NS * 3; e += 256)
        q[(e / 3) * 4 + (e % 3)] = xz2[e];
    __syncthreads();
    for (int s = t; s < NS; s += 256) {
        float qx = q[s*4+0], qy = q[s*4+1], qz = q[s*4+2];
        q[s*4+3] = qx*qx + qy*qy + qz*qz;
        q[s*4+0] = -2.0f*qx; q[s*4+1] = -2.0f*qy; q[s*4+2] = -2.0f*qz;
    }
    __syncthreads();

    const int p  = t & 63;
    const int ss = t >> 6;
    const int n  = n0 + p;
    const float px = xyz1[(b*NN + n)*3 + 0];
    const float py = xyz1[(b*NN + n)*3 + 1];
    const float pz = xyz1[(b*NN + n)*3 + 2];
    const float p2 = px*px + py*py + pz*pz;

    float d0 = 3.4e38f, d1 = 3.4e38f, d2v = 3.4e38f;
    int   i0 = 0, i1 = 0, i2 = 0;
    const int sbeg = ss * (NS/4);
    const int send = sbeg + (NS/4);
    #pragma unroll 4
    for (int s = sbeg; s < send; ++s) {
        float4 qq = *(const float4*)&q[s*4];
        float dp = fmaf(px, qq.x, fmaf(py, qq.y, fmaf(pz, qq.z, qq.w)));
        bool c0 = dp < d0, c1 = dp < d1, c2 = dp < d2v;
        int ni2 = c1 ? i1 : (c2 ? s : i2);
        int ni1 = c0 ? i0 : (c1 ? s : i1);
        int ni0 = c0 ? s  : i0;
        i2 = ni2; i1 = ni1; i0 = ni0;
        float nd2 = __builtin_amdgcn_fmed3f(d1, d2v, dp);
        float nd1 = __builtin_amdgcn_fmed3f(d0, d1, dp);
        float nd0 = fminf(d0, dp);
        d2v = nd2; d1 = nd1; d0 = nd0;
    }
    sd[ss][p][0] = d0; sd[ss][p][1] = d1; sd[ss][p][2] = d2v;
    sl[ss][p][0] = i0; sl[ss][p][1] = i1; sl[ss][p][2] = i2;
    __syncthreads();

    float w0r=0.f, w1r=0.f, w2r=0.f; int b0r=0, b1r=0, b2r=0;
    if (t < 64) {
        float dv[12]; int iv[12];
        #pragma unroll
        for (int m = 0; m < 4; ++m)
            #pragma unroll
            for (int k = 0; k < 3; ++k) {
                dv[m*3+k] = sd[m][t][k];
                iv[m*3+k] = sl[m][t][k];
            }
        float bd[3]; int bi[3];
        #pragma unroll
        for (int r = 0; r < 3; ++r) {
            int best = 0; float bv = dv[0];
            #pragma unroll
            for (int m = 1; m < 12; ++m)
                if (dv[m] < bv) { bv = dv[m]; best = m; }
            bd[r] = bv; bi[r] = iv[best]; dv[best] = 3.4e38f;
        }
        float r0 = 1.0f/(bd[0]+p2+EPS_ITP);
        float r1 = 1.0f/(bd[1]+p2+EPS_ITP);
        float r2 = 1.0f/(bd[2]+p2+EPS_ITP);
        float rsum = r0 + r1 + r2;
        w0r = r0/rsum; w1r = r1/rsum; w2r = r2/rsum;
        b0r = bi[0]; b1r = bi[1]; b2r = bi[2];
    }
    __syncthreads();
    if (t < 64) {
        sw[t][0] = w0r; sw[t][1] = w1r; sw[t][2] = w2r;
        si[t][0] = b0r; si[t][1] = b1r; si[t][2] = b2r;
    }
    __syncthreads();

    const float* p1 = points1 + (size_t)(b*NN + n0) * ND1;
    unsigned short* xrow = xb + (size_t)(b*NN + n0) * NCIN;
    #pragma unroll
    for (int i = 0; i < 8; ++i) {
        int e   = t + i*256;
        int row = e >> 5;
        int c4  = (e & 31) << 2;
        float4 v = *(const float4*)(p1 + (size_t)row*ND1 + c4);
        s16x4 o;
        o[0] = f2bf(v.x); o[1] = f2bf(v.y); o[2] = f2bf(v.z); o[3] = f2bf(v.w);
        *(s16x4*)(xrow + (size_t)row*NCIN + c4) = o;
    }
    const float* p2b = points2 + (size_t)b*NS*ND2;
    const int half = t >> 7;
    const int c2   = (t & 127) * 2;
    for (int j2 = 0; j2 < 32; ++j2) {
        int j = j2*2 + half;
        float w0 = sw[j][0], w1 = sw[j][1], w2 = sw[j][2];
        int   a0 = si[j][0], a1 = si[j][1], a2 = si[j][2];
        float2 v0 = *(const float2*)(p2b + (size_t)a0*ND2 + c2);
        float2 v1 = *(const float2*)(p2b + (size_t)a1*ND2 + c2);
        float2 v2 = *(const float2*)(p2b + (size_t)a2*ND2 + c2);
        float ox = w0*v0.x + w1*v1.x + w2*v2.x;
        float oy = w0*v0.y + w1*v1.y + w2*v2.y;
        s16x2 o; o[0] = f2bf(ox); o[1] = f2bf(oy);
        *(s16x2*)(xrow + (size_t)j*NCIN + ND1 + c2) = o;
    }
}

// ---------------------------------------------------------------------------
__global__ __launch_bounds__(256) void k_castw(
    const float* __restrict__ W1, const float* __restrict__ W2,
    unsigned short* __restrict__ Wb)
{
    int i = blockIdx.x * 256 + threadIdx.x;
    if (i < NC1*NCIN)                Wb[i] = (unsigned short)f2bf(W1[i]);
    else if (i < NC1*NCIN + NC2*NC1) Wb[i] = (unsigned short)f2bf(W2[i - NC1*NCIN]);
}

__global__ __launch_bounds__(256) void k_zero(float* __restrict__ p) {
    p[blockIdx.x * 256 + threadIdx.x] = 0.f;
}

// ---------------------------------------------------------------------------
// GEMM1 (MFMA) + fused stats: y1[b][n][o] = bf16(b1[o] + sum_c W1[o][c]*x[..])
// Block tile 128o x 128n, 4 waves (2o x 2n) — round-4-proven arrangement
// (waves pair-share A-rows and B-rows in L1). Fused stats epilogue:
// 16-lane shfl reduce -> atomicAdd S/S2 (kills standalone stats pass).
// ---------------------------------------------------------------------------
__global__ __launch_bounds__(256) void k_gemm1(
    const unsigned short* __restrict__ Xb, const unsigned short* __restrict__ W1b,
    const float* __restrict__ b1, unsigned short* __restrict__ y1,
    float* __restrict__ S, float* __restrict__ S2)
{
    const int t   = threadIdx.x;
    const int w   = t >> 6;
    const int wo  = w >> 1, wn = w & 1;
    const int l   = t & 63;
    const int l16 = l & 15, lk = l >> 4;
    const int n1  = blockIdx.x * 128 + wn * 64;
    const int o1  = blockIdx.y * 128 + wo * 64;
    const int b   = blockIdx.z;

    const unsigned short* xrow = Xb + (size_t)b * NN * NCIN;
    f32x4 acc[4][4] = {};

    const unsigned short* ap[4];
    const unsigned short* bp[4];
    #pragma unroll
    for (int m = 0; m < 4; ++m)
        ap[m] = W1b + (size_t)(o1 + m*16 + l16) * NCIN + lk*8;
    #pragma unroll
    for (int nn = 0; nn < 4; ++nn)
        bp[nn] = xrow + (size_t)(n1 + nn*16 + l16) * NCIN + lk*8;

    #pragma unroll 2
    for (int k0 = 0; k0 < NCIN; k0 += 32) {
        s16x8 af[4], bf[4];
        #pragma unroll
        for (int m = 0; m < 4; ++m) af[m] = *(const s16x8*)(ap[m] + k0);
        #pragma unroll
        for (int nn = 0; nn < 4; ++nn) bf[nn] = *(const s16x8*)(bp[nn] + k0);
        #pragma unroll
        for (int m = 0; m < 4; ++m)
            #pragma unroll
            for (int nn = 0; nn < 4; ++nn)
                acc[m][nn] = __builtin_amdgcn_mfma_f32_16x16x32_bf16(
                    af[m], bf[nn], acc[m][nn], 0, 0, 0);
    }

    unsigned short* yb = y1 + (size_t)b * NN * NC1;
    float sacc[4][4] = {};
    float qacc[4][4] = {};
    #pragma unroll
    for (int m = 0; m < 4; ++m) {
        f32x4 bias = *(const f32x4*)(b1 + o1 + m*16 + lk*4);
        #pragma unroll
        for (int nn = 0; nn < 4; ++nn) {
            int nidx = n1 + nn*16 + l16;
            f32x4 v = acc[m][nn] + bias;
            unsigned u01 = pkbf(v[0], v[1]);
            unsigned u23 = pkbf(v[2], v[3]);
            uint2 st; st.x = u01; st.y = u23;
            *(uint2*)(yb + (size_t)nidx*NC1 + o1 + m*16 + lk*4) = st;
            float r0 = bflo(u01), r1 = bfhi(u01), r2 = bflo(u23), r3 = bfhi(u23);
            sacc[m][0] += r0; qacc[m][0] += r0*r0;
            sacc[m][1] += r1; qacc[m][1] += r1*r1;
            sacc[m][2] += r2; qacc[m][2] += r2*r2;
            sacc[m][3] += r3; qacc[m][3] += r3*r3;
        }
    }
    #pragma unroll
    for (int m = 0; m < 4; ++m)
        #pragma unroll
        for (int j = 0; j < 4; ++j) {
            float s = sacc[m][j], q = qacc[m][j];
            #pragma unroll
            for (int off = 1; off < 16; off <<= 1) {
                s += __shfl_xor(s, off, 64);
                q += __shfl_xor(q, off, 64);
            }
            if (l16 == 0) {
                int o = o1 + m*16 + lk*4 + j;
                atomicAdd(&S [(size_t)b*NC1 + o], s);
                atomicAdd(&S2[(size_t)b*NC1 + o], q);
            }
        }
}

__global__ __launch_bounds__(256) void k_finstats(
    const float* __restrict__ S, const float* __restrict__ S2,
    float* __restrict__ mu, float* __restrict__ rs, int nent)
{
    int i = blockIdx.x * 256 + threadIdx.x;
    if (i < nent) {
        float m = S[i] * (1.0f/(float)NN);
        float var = S2[i] * (1.0f/(float)NN) - m*m;
        mu[i] = m;
        rs[i] = 1.0f / sqrtf(var + EPS_INORM);
    }
}

// ---------------------------------------------------------------------------
// Fold rs1 into W2 per batch: W2f[b][o][c] = bf16( W2[o][c] * rs1[b][c] )
// ---------------------------------------------------------------------------
__global__ __launch_bounds__(256) void k_foldw2(
    const unsigned short* __restrict__ W2b, const float* __restrict__ rs1,
    unsigned short* __restrict__ W2f)
{
    int i = blockIdx.x * 256 + threadIdx.x;   // over 8*128*256
    int b = i >> 15;
    int c = i & 255;
    float wv = __uint_as_float(((unsigned)W2b[i & 32767]) << 16);
    W2f[i] = (unsigned short)f2bf(wv * rs1[b*NC1 + c]);
}

// ---------------------------------------------------------------------------
// GEMM2 (MFMA) + fused stats: y2 = bf16(b2 + W2f * max(y1-mu1,0)); y1 once.
// Block tile 128o(full) x 128n, 4 waves (2o x 2n). (unchanged — fast)
// ---------------------------------------------------------------------------
__global__ __launch_bounds__(256) void k_gemm2(
    const unsigned short* __restrict__ y1, const unsigned short* __restrict__ W2f,
    const float* __restrict__ b2, const float* __restrict__ mu1,
    unsigned short* __restrict__ y2, float* __restrict__ S, float* __restrict__ S2)
{
    const int t   = threadIdx.x;
    const int w   = t >> 6;
    const int wo  = w >> 1, wn = w & 1;
    const int l   = t & 63;
    const int l16 = l & 15, lk = l >> 4;
    const int n1  = blockIdx.x * 128 + wn * 64;
    const int o1  = wo * 64;
    const int b   = blockIdx.y;

    const unsigned short* yrow = y1 + (size_t)b * NN * NC1;
    const unsigned short* wrow = W2f + (size_t)b * NC2 * NC1;
    const float* mu = mu1 + b * NC1;
    f32x4 acc[4][4] = {};

    const unsigned short* ap[4];
    const unsigned short* bp[4];
    #pragma unroll
    for (int m = 0; m < 4; ++m)
        ap[m] = wrow + (size_t)(o1 + m*16 + l16) * NC1 + lk*8;
    #pragma unroll
    for (int nn = 0; nn < 4; ++nn)
        bp[nn] = yrow + (size_t)(n1 + nn*16 + l16) * NC1 + lk*8;

    #pragma unroll 2
    for (int k0 = 0; k0 < NC1; k0 += 32) {
        f32x4 m0 = *(const f32x4*)(mu + k0 + lk*8);
        f32x4 m1 = *(const f32x4*)(mu + k0 + lk*8 + 4);
        s16x8 af[4], bf[4];
        #pragma unroll
        for (int m = 0; m < 4; ++m) af[m] = *(const s16x8*)(ap[m] + k0);
        #pragma unroll
        for (int nn = 0; nn < 4; ++nn) {
            uint4 ru = *(const uint4*)(bp[nn] + k0);
            float z0 = fmaxf(bflo(ru.x) - m0[0], 0.f);
            float z1 = fmaxf(bfhi(ru.x) - m0[1], 0.f);
            float z2 = fmaxf(bflo(ru.y) - m0[2], 0.f);
            float z3 = fmaxf(bfhi(ru.y) - m0[3], 0.f);
            float z4 = fmaxf(bflo(ru.z) - m1[0], 0.f);
            float z5 = fmaxf(bfhi(ru.z) - m1[1], 0.f);
            float z6 = fmaxf(bflo(ru.w) - m1[2], 0.f);
            float z7 = fmaxf(bfhi(ru.w) - m1[3], 0.f);
            union { uint4 u; s16x8 s; } cv;
            cv.u.x = pkbf(z0, z1); cv.u.y = pkbf(z2, z3);
            cv.u.z = pkbf(z4, z5); cv.u.w = pkbf(z6, z7);
            bf[nn] = cv.s;
        }
        #pragma unroll
        for (int m = 0; m < 4; ++m)
            #pragma unroll
            for (int nn = 0; nn < 4; ++nn)
                acc[m][nn] = __builtin_amdgcn_mfma_f32_16x16x32_bf16(
                    af[m], bf[nn], acc[m][nn], 0, 0, 0);
    }

    unsigned short* yb = y2 + (size_t)b * NN * NC2;
    float sacc[4][4] = {};
    float qacc[4][4] = {};
    #pragma unroll
    for (int m = 0; m < 4; ++m) {
        f32x4 bias = *(const f32x4*)(b2 + o1 + m*16 + lk*4);
        #pragma unroll
        for (int nn = 0; nn < 4; ++nn) {
            int nidx = n1 + nn*16 + l16;
            f32x4 v = acc[m][nn] + bias;
            unsigned u01 = pkbf(v[0], v[1]);
            unsigned u23 = pkbf(v[2], v[3]);
            uint2 st; st.x = u01; st.y = u23;
            *(uint2*)(yb + (size_t)nidx*NC2 + o1 + m*16 + lk*4) = st;
            float r0 = bflo(u01), r1 = bfhi(u01), r2 = bflo(u23), r3 = bfhi(u23);
            sacc[m][0] += r0; qacc[m][0] += r0*r0;
            sacc[m][1] += r1; qacc[m][1] += r1*r1;
            sacc[m][2] += r2; qacc[m][2] += r2*r2;
            sacc[m][3] += r3; qacc[m][3] += r3*r3;
        }
    }
    #pragma unroll
    for (int m = 0; m < 4; ++m)
        #pragma unroll
        for (int j = 0; j < 4; ++j) {
            float s = sacc[m][j], q = qacc[m][j];
            #pragma unroll
            for (int off = 1; off < 16; off <<= 1) {
                s += __shfl_xor(s, off, 64);
                q += __shfl_xor(q, off, 64);
            }
            if (l16 == 0) {
                int o = o1 + m*16 + lk*4 + j;
                atomicAdd(&S [(size_t)b*NC2 + o], s);
                atomicAdd(&S2[(size_t)b*NC2 + o], q);
            }
        }
}

// ---------------------------------------------------------------------------
// Final: out[b][n][o] = relu((y2[b][n][o]-mu2[o])*rs2[o])  f32
// ---------------------------------------------------------------------------
__global__ __launch_bounds__(256) void k_final(
    const unsigned short* __restrict__ y2, const float* __restrict__ mu2,
    const float* __restrict__ rs2, float* __restrict__ out)
{
    const int total4 = NB * NN * NC2 / 4;
    const int perb4  = NN * NC2 / 4;
    for (int i = blockIdx.x * 256 + threadIdx.x; i < total4; i += gridDim.x * 256) {
        int b  = i / perb4;
        int c4 = (i & 31) * 4;
        uint2 u = *(const uint2*)(y2 + (size_t)i*4);
        f32x4 m = *(const f32x4*)(mu2 + b*NC2 + c4);
        f32x4 r = *(const f32x4*)(rs2 + b*NC2 + c4);
        f32x4 o;
        o[0] = fmaxf(0.f, (bflo(u.x) - m[0]) * r[0]);
        o[1] = fmaxf(0.f, (bfhi(u.x) - m[1]) * r[1]);
        o[2] = fmaxf(0.f, (bflo(u.y) - m[2]) * r[2]);
        o[3] = fmaxf(0.f, (bfhi(u.y) - m[3]) * r[3]);
        *(f32x4*)(out + (size_t)i*4) = o;
    }
}

// ---------------------------------------------------------------------------
extern "C" void kernel_launch(void* const* d_in, const int* in_sizes, int n_in,
                              void* d_out, int out_size, void* d_ws, size_t ws_size,
                              hipStream_t stream) {
    const float* xyz1    = (const float*)d_in[0];
    const float* xyz2    = (const float*)d_in[1];
    const float* points1 = (const float*)d_in[2];
    const float* points2 = (const float*)d_in[3];
    const float* W1      = (const float*)d_in[4];
    const float* b1      = (const float*)d_in[5];
    const float* W2      = (const float*)d_in[6];
    const float* b2      = (const float*)d_in[7];
    float* out = (float*)d_out;

    char* ws = (char*)d_ws;
    unsigned short* xb  = (unsigned short*)(ws);             // 50,331,648 B
    unsigned short* y1b = (unsigned short*)(ws + 50331648);  // 33,554,432 B
    unsigned short* y2b = (unsigned short*)(ws + 83886080);  // 16,777,216 B
    unsigned short* Wb  = (unsigned short*)(ws + 100663296); // 262,144 B
    unsigned short* W2f = (unsigned short*)(ws + 100925440); // 524,288 B
    float* accb = (float*)(ws + 101449728);                  // 6144 f (zeroed)
    float* S1a = accb;
    float* S2a = accb + 2048;
    float* T1a = accb + 4096;
    float* T2a = accb + 5120;
    float* prm = (float*)(ws + 101474304);
    float* mu1 = prm;
    float* rs1 = prm + 2048;
    float* mu2 = prm + 4096;
    float* rs2 = prm + 5120;
    unsigned short* W2b = Wb + NC1*NCIN;

    k_zero<<<24, 256, 0, stream>>>(accb);
    k_castw<<<512, 256, 0, stream>>>(W1, W2, Wb);
    k_knn_interp<<<dim3(NN/64, NB), 256, 0, stream>>>(xyz1, xyz2, points1, points2, xb);
    k_gemm1<<<dim3(NN/128, NC1/128, NB), 256, 0, stream>>>(xb, Wb, b1, y1b, S1a, S2a);
    k_finstats<<<8, 256, 0, stream>>>(S1a, S2a, mu1, rs1, NB*NC1);
    k_foldw2<<<1024, 256, 0, stream>>>(W2b, rs1, W2f);
    k_gemm2<<<dim3(NN/128, NB), 256, 0, stream>>>(y1b, W2f, b2, mu1, y2b, T1a, T2a);
    k_finstats<<<4, 256, 0, stream>>>(T1a, T2a, mu2, rs2, NB*NC2);
    k_final<<<2048, 256, 0, stream>>>(y2b, mu2, rs2, out);
}

// Round 8
// 264.861 us; speedup vs baseline: 1.1425x; 1.1425x over previous
//
#include <hip/hip_runtime.h>
#include <math.h>

#define NB   8
#define NN   8192
#define NS   2048
#define ND1  128
#define ND2  256
#define NCIN 384
#define NC1  256
#define NC2  128

#define EPS_ITP 1e-8f
#define EPS_INORM 1e-5f

typedef float f32x4 __attribute__((ext_vector_type(4)));
typedef short s16x8 __attribute__((ext_vector_type(8)));
typedef short s16x4 __attribute__((ext_vector_type(4)));
typedef short s16x2 __attribute__((ext_vector_type(2)));

// RNE float->bf16 (finite inputs)
static __device__ __forceinline__ short f2bf(float f) {
    unsigned u = __float_as_uint(f);
    unsigned r = (u + 0x7FFFu + ((u >> 16) & 1u)) >> 16;
    return (short)r;
}
static __device__ __forceinline__ float bflo(unsigned u) { return __uint_as_float(u << 16); }
static __device__ __forceinline__ float bfhi(unsigned u) { return __uint_as_float(u & 0xFFFF0000u); }
// pack 2 f32 -> 2 bf16 in one u32 (lo=a, hi=b), RNE
static __device__ __forceinline__ unsigned pkbf(float a, float b) {
    unsigned r;
    asm("v_cvt_pk_bf16_f32 %0, %1, %2" : "=v"(r) : "v"(a), "v"(b));
    return r;
}

// ---------------------------------------------------------------------------
// Kernel 1: 3-NN + inverse-distance interp + concat -> x bf16 [B][N][384]
// 32 points/block, 8 slices/point; q staged in TWO 16KB halves (LDS 22.5KB ->
// 7 blocks/CU, 28 waves). Slice ranges globally contiguous: slice ss covers
// [ss*256, ss*256+256), half h holds its [h*128, h*128+128) sub-range and
// scan registers persist across halves -> tie-break identical to monolithic.
// ---------------------------------------------------------------------------
__global__ __launch_bounds__(256) void k_knn_interp(
    const float* __restrict__ xyz1, const float* __restrict__ xyz2,
    const float* __restrict__ points1, const float* __restrict__ points2,
    unsigned short* __restrict__ xb)
{
    __shared__ float q[1024 * 4];      // 16384 B (one half)
    __shared__ float sd[8][32][3];     // 3072 B
    __shared__ int   sl[8][32][3];     // 3072 B
    float (*sw)[3] = (float(*)[3])&sd[0][0][0];   // overlay after merge
    int   (*si)[3] = (int  (*)[3])&sl[0][0][0];

    const int t  = threadIdx.x;
    const int b  = blockIdx.y;
    const int n0 = blockIdx.x * 32;

    const float* xz2 = xyz2 + b * NS * 3;

    const int p  = t & 31;     // point within block
    const int ss = t >> 5;     // slice (8)
    const int n  = n0 + p;
    const float px = xyz1[(b*NN + n)*3 + 0];
    const float py = xyz1[(b*NN + n)*3 + 1];
    const float pz = xyz1[(b*NN + n)*3 + 2];
    const float p2 = px*px + py*py + pz*pz;

    float d0 = 3.4e38f, d1 = 3.4e38f, d2v = 3.4e38f;
    int   i0 = 0, i1 = 0, i2 = 0;

    for (int hh = 0; hh < 2; ++hh) {
        __syncthreads();   // protect previous half's reads
        // LDS slot j holds global s = (j>>7)*256 + hh*128 + (j&127)
        for (int j = t; j < 1024; j += 256) {
            int sg = ((j >> 7) << 8) + hh*128 + (j & 127);
            float qx = xz2[sg*3+0], qy = xz2[sg*3+1], qz = xz2[sg*3+2];
            q[j*4+0] = -2.0f*qx; q[j*4+1] = -2.0f*qy; q[j*4+2] = -2.0f*qz;
            q[j*4+3] = qx*qx + qy*qy + qz*qz;
        }
        __syncthreads();
        const int sbase = ss*256 + hh*128;   // global s of k=0
        #pragma unroll 4
        for (int k = 0; k < 128; ++k) {
            float4 qq = *(const float4*)&q[(ss*128 + k)*4];
            float dp = fmaf(px, qq.x, fmaf(py, qq.y, fmaf(pz, qq.z, qq.w)));
            int s = sbase + k;
            bool c0 = dp < d0, c1 = dp < d1, c2 = dp < d2v;
            int ni2 = c1 ? i1 : (c2 ? s : i2);
            int ni1 = c0 ? i0 : (c1 ? s : i1);
            int ni0 = c0 ? s  : i0;
            i2 = ni2; i1 = ni1; i0 = ni0;
            float nd2 = __builtin_amdgcn_fmed3f(d1, d2v, dp);
            float nd1 = __builtin_amdgcn_fmed3f(d0, d1, dp);
            float nd0 = fminf(d0, dp);
            d2v = nd2; d1 = nd1; d0 = nd0;
        }
    }
    __syncthreads();
    sd[ss][p][0] = d0; sd[ss][p][1] = d1; sd[ss][p][2] = d2v;
    sl[ss][p][0] = i0; sl[ss][p][1] = i1; sl[ss][p][2] = i2;
    __syncthreads();

    // merge 8 slices' top-3 (24 entries, LDS-resident) -> global top-3
    float w0r=0.f, w1r=0.f, w2r=0.f; int b0r=0, b1r=0, b2r=0;
    if (t < 32) {
        float bd[3]; int bi[3];
        #pragma unroll
        for (int r = 0; r < 3; ++r) {
            float bv = 3.4e38f; int bm = 0, bk = 0;
            #pragma unroll
            for (int m = 0; m < 8; ++m)
                #pragma unroll
                for (int k = 0; k < 3; ++k) {
                    float v = sd[m][t][k];
                    if (v < bv) { bv = v; bm = m; bk = k; }
                }
            bd[r] = bv; bi[r] = sl[bm][t][bk];
            sd[bm][t][bk] = 3.4e38f;
        }
        float r0 = 1.0f/(bd[0]+p2+EPS_ITP);
        float r1 = 1.0f/(bd[1]+p2+EPS_ITP);
        float r2 = 1.0f/(bd[2]+p2+EPS_ITP);
        float rsum = r0 + r1 + r2;
        w0r = r0/rsum; w1r = r1/rsum; w2r = r2/rsum;
        b0r = bi[0]; b1r = bi[1]; b2r = bi[2];
    }
    __syncthreads();   // sd/sl reads done; safe to overlay
    if (t < 32) {
        sw[t][0] = w0r; sw[t][1] = w1r; sw[t][2] = w2r;
        si[t][0] = b0r; si[t][1] = b1r; si[t][2] = b2r;
    }
    __syncthreads();

    // points1 -> x[:, 0:128] bf16 (32 rows x 32 float4; 4 per thread)
    const float* p1 = points1 + (size_t)(b*NN + n0) * ND1;
    unsigned short* xrow = xb + (size_t)(b*NN + n0) * NCIN;
    #pragma unroll
    for (int i = 0; i < 4; ++i) {
        int e   = t + i*256;
        int row = e >> 5;
        int c4  = (e & 31) << 2;
        float4 v = *(const float4*)(p1 + (size_t)row*ND1 + c4);
        s16x4 o;
        o[0] = f2bf(v.x); o[1] = f2bf(v.y); o[2] = f2bf(v.z); o[3] = f2bf(v.w);
        *(s16x4*)(xrow + (size_t)row*NCIN + c4) = o;
    }
    // interp -> x[:, 128:384] bf16 (2 rows per iter, 2 ch/thread)
    const float* p2b = points2 + (size_t)b*NS*ND2;
    const int half = t >> 7;
    const int c2   = (t & 127) * 2;
    for (int j2 = 0; j2 < 16; ++j2) {
        int j = j2*2 + half;
        float w0 = sw[j][0], w1 = sw[j][1], w2 = sw[j][2];
        int   a0 = si[j][0], a1 = si[j][1], a2 = si[j][2];
        float2 v0 = *(const float2*)(p2b + (size_t)a0*ND2 + c2);
        float2 v1 = *(const float2*)(p2b + (size_t)a1*ND2 + c2);
        float2 v2 = *(const float2*)(p2b + (size_t)a2*ND2 + c2);
        float ox = w0*v0.x + w1*v1.x + w2*v2.x;
        float oy = w0*v0.y + w1*v1.y + w2*v2.y;
        s16x2 o; o[0] = f2bf(ox); o[1] = f2bf(oy);
        *(s16x2*)(xrow + (size_t)j*NCIN + ND1 + c2) = o;
    }
}

// ---------------------------------------------------------------------------
__global__ __launch_bounds__(256) void k_castw(
    const float* __restrict__ W1, const float* __restrict__ W2,
    unsigned short* __restrict__ Wb)
{
    int i = blockIdx.x * 256 + threadIdx.x;
    if (i < NC1*NCIN)                Wb[i] = (unsigned short)f2bf(W1[i]);
    else if (i < NC1*NCIN + NC2*NC1) Wb[i] = (unsigned short)f2bf(W2[i - NC1*NCIN]);
}

// ---------------------------------------------------------------------------
// GEMM1 (MFMA): y1[b][n][o] = bf16( b1[o] + sum_c W1[o][c]*x[b][n][c] )
// Block tile 128o x 128n, 4 waves (2o x 2n). UNFUSED (R5-proven, ~27us).
// ---------------------------------------------------------------------------
__global__ __launch_bounds__(256) void k_gemm1(
    const unsigned short* __restrict__ Xb, const unsigned short* __restrict__ W1b,
    const float* __restrict__ b1, unsigned short* __restrict__ y1)
{
    const int t   = threadIdx.x;
    const int w   = t >> 6;
    const int wo  = w >> 1, wn = w & 1;
    const int l   = t & 63;
    const int l16 = l & 15, lk = l >> 4;
    const int n1  = blockIdx.x * 128 + wn * 64;
    const int o1  = blockIdx.y * 128 + wo * 64;
    const int b   = blockIdx.z;

    const unsigned short* xrow = Xb + (size_t)b * NN * NCIN;
    f32x4 acc[4][4] = {};

    const unsigned short* ap[4];
    const unsigned short* bp[4];
    #pragma unroll
    for (int m = 0; m < 4; ++m)
        ap[m] = W1b + (size_t)(o1 + m*16 + l16) * NCIN + lk*8;
    #pragma unroll
    for (int nn = 0; nn < 4; ++nn)
        bp[nn] = xrow + (size_t)(n1 + nn*16 + l16) * NCIN + lk*8;

    #pragma unroll 2
    for (int k0 = 0; k0 < NCIN; k0 += 32) {
        s16x8 af[4], bf[4];
        #pragma unroll
        for (int m = 0; m < 4; ++m) af[m] = *(const s16x8*)(ap[m] + k0);
        #pragma unroll
        for (int nn = 0; nn < 4; ++nn) bf[nn] = *(const s16x8*)(bp[nn] + k0);
        #pragma unroll
        for (int m = 0; m < 4; ++m)
            #pragma unroll
            for (int nn = 0; nn < 4; ++nn)
                acc[m][nn] = __builtin_amdgcn_mfma_f32_16x16x32_bf16(
                    af[m], bf[nn], acc[m][nn], 0, 0, 0);
    }

    unsigned short* yb = y1 + (size_t)b * NN * NC1;
    #pragma unroll
    for (int m = 0; m < 4; ++m) {
        f32x4 bias = *(const f32x4*)(b1 + o1 + m*16 + lk*4);
        #pragma unroll
        for (int nn = 0; nn < 4; ++nn) {
            int nidx = n1 + nn*16 + l16;
            f32x4 v = acc[m][nn] + bias;
            s16x4 o;
            o[0] = f2bf(v[0]); o[1] = f2bf(v[1]); o[2] = f2bf(v[2]); o[3] = f2bf(v[3]);
            *(s16x4*)(yb + (size_t)nidx*NC1 + o1 + m*16 + lk*4) = o;
        }
    }
}

// ---------------------------------------------------------------------------
// Stats stage A (y1): per-chunk partial sums, NO atomics.
// Grid (128,8): chunk = 64 n-rows. P layout: [b][chunk][2][256] f32.
// ---------------------------------------------------------------------------
__global__ __launch_bounds__(256) void k_stats1a(
    const unsigned short* __restrict__ y1, float* __restrict__ P)
{
    const int t = threadIdx.x;
    const int b = blockIdx.y;
    const int chunk = blockIdx.x;
    const int c = t & 127, h = t >> 7;
    const unsigned short* p = y1 + ((size_t)(b*NN + chunk*64 + h))*NC1 + c*2;
    float sl=0.f, sh=0.f, ql=0.f, qh=0.f;
    for (int r = 0; r < 32; ++r) {
        unsigned u = *(const unsigned*)(p + (size_t)(2*r)*NC1);
        float flo = bflo(u), fhi = bfhi(u);
        sl += flo; ql += flo*flo; sh += fhi; qh += fhi*fhi;
    }
    __shared__ float red[4][128];
    if (h) { red[0][c]=sl; red[1][c]=sh; red[2][c]=ql; red[3][c]=qh; }
    __syncthreads();
    if (!h) {
        sl += red[0][c]; sh += red[1][c]; ql += red[2][c]; qh += red[3][c];
        float* dst = P + ((size_t)(b*128 + chunk)*2)*NC1;
        dst[2*c] = sl; dst[2*c+1] = sh;
        dst[NC1 + 2*c] = ql; dst[NC1 + 2*c+1] = qh;
    }
}

// Stage B (y1): reduce 128 chunks -> mu, rs. 8 blocks x 256 threads.
__global__ __launch_bounds__(256) void k_stats1b(
    const float* __restrict__ P, float* __restrict__ mu, float* __restrict__ rs)
{
    int i = blockIdx.x * 256 + threadIdx.x;   // i = b*256 + o
    int b = i >> 8, o = i & 255;
    const float* src = P + (size_t)b*128*2*NC1;
    float s = 0.f, q = 0.f;
    for (int ch = 0; ch < 128; ++ch) {
        s += src[(size_t)ch*2*NC1 + o];
        q += src[(size_t)ch*2*NC1 + NC1 + o];
    }
    float m = s * (1.0f/(float)NN);
    float var = q * (1.0f/(float)NN) - m*m;
    mu[i] = m;
    rs[i] = 1.0f / sqrtf(var + EPS_INORM);
}

// ---------------------------------------------------------------------------
// Fold rs1 into W2 per batch: W2f[b][o][c] = bf16( W2[o][c] * rs1[b][c] )
// ---------------------------------------------------------------------------
__global__ __launch_bounds__(256) void k_foldw2(
    const unsigned short* __restrict__ W2b, const float* __restrict__ rs1,
    unsigned short* __restrict__ W2f)
{
    int i = blockIdx.x * 256 + threadIdx.x;   // over 8*128*256
    int b = i >> 15;
    int c = i & 255;
    float wv = __uint_as_float(((unsigned)W2b[i & 32767]) << 16);
    W2f[i] = (unsigned short)f2bf(wv * rs1[b*NC1 + c]);
}

// ---------------------------------------------------------------------------
// GEMM2 (MFMA): y2[b][n][o] = bf16( b2[o] + sum_c W2f[b][o][c]*max(y1-mu1,0) )
// Block tile 128o(full) x 128n, 4 waves (2o x 2n). UNFUSED (R5-proven).
// ---------------------------------------------------------------------------
__global__ __launch_bounds__(256) void k_gemm2(
    const unsigned short* __restrict__ y1, const unsigned short* __restrict__ W2f,
    const float* __restrict__ b2, const float* __restrict__ mu1,
    unsigned short* __restrict__ y2)
{
    const int t   = threadIdx.x;
    const int w   = t >> 6;
    const int wo  = w >> 1, wn = w & 1;
    const int l   = t & 63;
    const int l16 = l & 15, lk = l >> 4;
    const int n1  = blockIdx.x * 128 + wn * 64;
    const int o1  = wo * 64;
    const int b   = blockIdx.y;

    const unsigned short* yrow = y1 + (size_t)b * NN * NC1;
    const unsigned short* wrow = W2f + (size_t)b * NC2 * NC1;
    const float* mu = mu1 + b * NC1;
    f32x4 acc[4][4] = {};

    const unsigned short* ap[4];
    const unsigned short* bp[4];
    #pragma unroll
    for (int m = 0; m < 4; ++m)
        ap[m] = wrow + (size_t)(o1 + m*16 + l16) * NC1 + lk*8;
    #pragma unroll
    for (int nn = 0; nn < 4; ++nn)
        bp[nn] = yrow + (size_t)(n1 + nn*16 + l16) * NC1 + lk*8;

    #pragma unroll 2
    for (int k0 = 0; k0 < NC1; k0 += 32) {
        f32x4 m0 = *(const f32x4*)(mu + k0 + lk*8);
        f32x4 m1 = *(const f32x4*)(mu + k0 + lk*8 + 4);
        s16x8 af[4], bf[4];
        #pragma unroll
        for (int m = 0; m < 4; ++m) af[m] = *(const s16x8*)(ap[m] + k0);
        #pragma unroll
        for (int nn = 0; nn < 4; ++nn) {
            uint4 ru = *(const uint4*)(bp[nn] + k0);
            float z0 = fmaxf(bflo(ru.x) - m0[0], 0.f);
            float z1 = fmaxf(bfhi(ru.x) - m0[1], 0.f);
            float z2 = fmaxf(bflo(ru.y) - m0[2], 0.f);
            float z3 = fmaxf(bfhi(ru.y) - m0[3], 0.f);
            float z4 = fmaxf(bflo(ru.z) - m1[0], 0.f);
            float z5 = fmaxf(bfhi(ru.z) - m1[1], 0.f);
            float z6 = fmaxf(bflo(ru.w) - m1[2], 0.f);
            float z7 = fmaxf(bfhi(ru.w) - m1[3], 0.f);
            union { uint4 u; s16x8 s; } cv;
            cv.u.x = pkbf(z0, z1); cv.u.y = pkbf(z2, z3);
            cv.u.z = pkbf(z4, z5); cv.u.w = pkbf(z6, z7);
            bf[nn] = cv.s;
        }
        #pragma unroll
        for (int m = 0; m < 4; ++m)
            #pragma unroll
            for (int nn = 0; nn < 4; ++nn)
                acc[m][nn] = __builtin_amdgcn_mfma_f32_16x16x32_bf16(
                    af[m], bf[nn], acc[m][nn], 0, 0, 0);
    }

    unsigned short* yb = y2 + (size_t)b * NN * NC2;
    #pragma unroll
    for (int m = 0; m < 4; ++m) {
        f32x4 bias = *(const f32x4*)(b2 + o1 + m*16 + lk*4);
        #pragma unroll
        for (int nn = 0; nn < 4; ++nn) {
            int nidx = n1 + nn*16 + l16;
            f32x4 v = acc[m][nn] + bias;
            s16x4 o;
            o[0] = f2bf(v[0]); o[1] = f2bf(v[1]); o[2] = f2bf(v[2]); o[3] = f2bf(v[3]);
            *(s16x4*)(yb + (size_t)nidx*NC2 + o1 + m*16 + lk*4) = o;
        }
    }
}

// ---------------------------------------------------------------------------
// Stats stage A (y2): Grid (128,8), chunk = 64 rows. P2: [b][chunk][2][128].
// ---------------------------------------------------------------------------
__global__ __launch_bounds__(256) void k_stats2a(
    const unsigned short* __restrict__ y2, float* __restrict__ P)
{
    const int t = threadIdx.x;
    const int b = blockIdx.y;
    const int chunk = blockIdx.x;
    const int c = t & 63, h = t >> 6;
    const unsigned short* p = y2 + ((size_t)(b*NN + chunk*64 + h))*NC2 + c*2;
    float sl=0.f, sh=0.f, ql=0.f, qh=0.f;
    for (int r = 0; r < 16; ++r) {
        unsigned u = *(const unsigned*)(p + (size_t)(4*r)*NC2);
        float flo = bflo(u), fhi = bfhi(u);
        sl += flo; ql += flo*flo; sh += fhi; qh += fhi*fhi;
    }
    __shared__ float red[3][4][64];
    if (h) { red[h-1][0][c]=sl; red[h-1][1][c]=sh; red[h-1][2][c]=ql; red[h-1][3][c]=qh; }
    __syncthreads();
    if (!h) {
        #pragma unroll
        for (int g = 0; g < 3; ++g) {
            sl += red[g][0][c]; sh += red[g][1][c];
            ql += red[g][2][c]; qh += red[g][3][c];
        }
        float* dst = P + ((size_t)(b*128 + chunk)*2)*NC2;
        dst[2*c] = sl; dst[2*c+1] = sh;
        dst[NC2 + 2*c] = ql; dst[NC2 + 2*c+1] = qh;
    }
}

// Stage B (y2): 4 blocks x 256 threads -> mu2, rs2.
__global__ __launch_bounds__(256) void k_stats2b(
    const float* __restrict__ P, float* __restrict__ mu, float* __restrict__ rs)
{
    int i = blockIdx.x * 256 + threadIdx.x;   // i = b*128 + o
    int b = i >> 7, o = i & 127;
    const float* src = P + (size_t)b*128*2*NC2;
    float s = 0.f, q = 0.f;
    for (int ch = 0; ch < 128; ++ch) {
        s += src[(size_t)ch*2*NC2 + o];
        q += src[(size_t)ch*2*NC2 + NC2 + o];
    }
    float m = s * (1.0f/(float)NN);
    float var = q * (1.0f/(float)NN) - m*m;
    mu[i] = m;
    rs[i] = 1.0f / sqrtf(var + EPS_INORM);
}

// ---------------------------------------------------------------------------
// Final: out[b][n][o] = relu((y2[b][n][o]-mu2[o])*rs2[o])  f32
// ---------------------------------------------------------------------------
__global__ __launch_bounds__(256) void k_final(
    const unsigned short* __restrict__ y2, const float* __restrict__ mu2,
    const float* __restrict__ rs2, float* __restrict__ out)
{
    const int total4 = NB * NN * NC2 / 4;
    const int perb4  = NN * NC2 / 4;
    for (int i = blockIdx.x * 256 + threadIdx.x; i < total4; i += gridDim.x * 256) {
        int b  = i / perb4;
        int c4 = (i & 31) * 4;
        uint2 u = *(const uint2*)(y2 + (size_t)i*4);
        f32x4 m = *(const f32x4*)(mu2 + b*NC2 + c4);
        f32x4 r = *(const f32x4*)(rs2 + b*NC2 + c4);
        f32x4 o;
        o[0] = fmaxf(0.f, (bflo(u.x) - m[0]) * r[0]);
        o[1] = fmaxf(0.f, (bfhi(u.x) - m[1]) * r[1]);
        o[2] = fmaxf(0.f, (bflo(u.y) - m[2]) * r[2]);
        o[3] = fmaxf(0.f, (bfhi(u.y) - m[3]) * r[3]);
        *(f32x4*)(out + (size_t)i*4) = o;
    }
}

// ---------------------------------------------------------------------------
extern "C" void kernel_launch(void* const* d_in, const int* in_sizes, int n_in,
                              void* d_out, int out_size, void* d_ws, size_t ws_size,
                              hipStream_t stream) {
    const float* xyz1    = (const float*)d_in[0];
    const float* xyz2    = (const float*)d_in[1];
    const float* points1 = (const float*)d_in[2];
    const float* points2 = (const float*)d_in[3];
    const float* W1      = (const float*)d_in[4];
    const float* b1      = (const float*)d_in[5];
    const float* W2      = (const float*)d_in[6];
    const float* b2      = (const float*)d_in[7];
    float* out = (float*)d_out;

    char* ws = (char*)d_ws;
    unsigned short* xb  = (unsigned short*)(ws);             // 50,331,648 B
    unsigned short* y1b = (unsigned short*)(ws + 50331648);  // 33,554,432 B
    unsigned short* y2b = (unsigned short*)(ws + 83886080);  // 16,777,216 B
    unsigned short* Wb  = (unsigned short*)(ws + 100663296); // 262,144 B
    unsigned short* W2f = (unsigned short*)(ws + 100925440); // 524,288 B
    float* P1  = (float*)(ws + 101449728);                   // 2,097,152 B
    float* P2  = (float*)(ws + 103546880);                   // 1,048,576 B
    float* prm = (float*)(ws + 104595456);                   // 24,576 B
    float* mu1 = prm;
    float* rs1 = prm + 2048;
    float* mu2 = prm + 4096;
    float* rs2 = prm + 5120;
    unsigned short* W2b = Wb + NC1*NCIN;

    k_castw<<<512, 256, 0, stream>>>(W1, W2, Wb);
    k_knn_interp<<<dim3(NN/32, NB), 256, 0, stream>>>(xyz1, xyz2, points1, points2, xb);
    k_gemm1<<<dim3(NN/128, NC1/128, NB), 256, 0, stream>>>(xb, Wb, b1, y1b);
    k_stats1a<<<dim3(128, NB), 256, 0, stream>>>(y1b, P1);
    k_stats1b<<<8, 256, 0, stream>>>(P1, mu1, rs1);
    k_foldw2<<<1024, 256, 0, stream>>>(W2b, rs1, W2f);
    k_gemm2<<<dim3(NN/128, NB), 256, 0, stream>>>(y1b, W2f, b2, mu1, y2b);
    k_stats2a<<<dim3(128, NB), 256, 0, stream>>>(y2b, P2);
    k_stats2b<<<4, 256, 0, stream>>>(P2, mu2, rs2);
    k_final<<<2048, 256, 0, stream>>>(y2b, mu2, rs2, out);
}